// Round 5
// baseline (1834.060 us; speedup 1.0000x reference)
//
#include <hip/hip_runtime.h>
#include <hip/hip_bf16.h>
#include <math.h>

#define N_NODES 65536
#define N_EDGES 262144
#define BATCHSZ 2048
#define F_IN    78
#define GENES   735
#define GOUT    512
#define HEADS   8
#define HID     64
#define TOT_E   (N_EDGES + N_NODES)   // 327680

typedef unsigned short u16;
typedef unsigned int   u32;

__device__ __forceinline__ float bf2f(u32 h) {
    u32 u = h << 16;
    return __uint_as_float(u);
}
__device__ __forceinline__ u16 f2bf(float f) {
    u32 u = __float_as_uint(f);
    u32 r = (u + 0x7FFFu + ((u >> 16) & 1u)) >> 16;   // round-to-nearest-even
    return (u16)r;
}

// ---------------- tiled GEMM, f32 compute; A/C optionally bf16 ----------------
// C[M,N] = A[M,K] @ B[K,N]; B always f32 (weights). ldc for C.
// EPI: 0=none, 2=relu(acc+bias), 3=bn-relu
template<int EPI, int ABF, int CBF>
__global__ __launch_bounds__(256) void gemm_tile(
    const void* __restrict__ Av, const float* __restrict__ B, void* __restrict__ Cv,
    int M, int N, int K, int ldc,
    const float* __restrict__ bias,
    const float* __restrict__ bng, const float* __restrict__ bnb,
    const float* __restrict__ bnm, const float* __restrict__ bnv)
{
    __shared__ float As[64][33];
    __shared__ float Bs[32][64];
    const float* Af = (const float*)Av;
    const u16*   Ab = (const u16*)Av;
    int t  = threadIdx.x;
    int bm = blockIdx.x * 64, bn = blockIdx.y * 64;
    int ty = t >> 4, tx = t & 15;
    float acc[4][4] = {};
    for (int k0 = 0; k0 < K; k0 += 32) {
        #pragma unroll
        for (int i = 0; i < 8; ++i) {
            int idx = t + i * 256;
            int r = idx >> 5, kk = idx & 31;
            int gr = bm + r, gk = k0 + kk;
            float v = 0.f;
            if (gr < M && gk < K)
                v = ABF ? bf2f(Ab[(size_t)gr * K + gk]) : Af[(size_t)gr * K + gk];
            As[r][kk] = v;
        }
        #pragma unroll
        for (int i = 0; i < 8; ++i) {
            int idx = t + i * 256;
            int kk = idx >> 6, c = idx & 63;
            int gk = k0 + kk, gc = bn + c;
            Bs[kk][c] = (gk < K && gc < N) ? B[(size_t)gk * N + gc] : 0.f;
        }
        __syncthreads();
        #pragma unroll
        for (int k = 0; k < 32; ++k) {
            float a0 = As[ty*4+0][k], a1 = As[ty*4+1][k];
            float a2 = As[ty*4+2][k], a3 = As[ty*4+3][k];
            float4 b = *(const float4*)&Bs[k][tx*4];
            acc[0][0] += a0*b.x; acc[0][1] += a0*b.y; acc[0][2] += a0*b.z; acc[0][3] += a0*b.w;
            acc[1][0] += a1*b.x; acc[1][1] += a1*b.y; acc[1][2] += a1*b.z; acc[1][3] += a1*b.w;
            acc[2][0] += a2*b.x; acc[2][1] += a2*b.y; acc[2][2] += a2*b.z; acc[2][3] += a2*b.w;
            acc[3][0] += a3*b.x; acc[3][1] += a3*b.y; acc[3][2] += a3*b.z; acc[3][3] += a3*b.w;
        }
        __syncthreads();
    }
    #pragma unroll
    for (int i = 0; i < 4; ++i) {
        int gr = bm + ty*4 + i;
        if (gr >= M) continue;
        #pragma unroll
        for (int j = 0; j < 4; ++j) {
            int gc = bn + tx*4 + j;
            if (gc >= N) continue;
            float v = acc[i][j];
            if (EPI == 2) { v += bias[gc]; v = fmaxf(v, 0.f); }
            if (EPI == 3) {
                float s = bng[gc] * rsqrtf(bnv[gc] + 1e-5f);
                v = (v + bias[gc] - bnm[gc]) * s + bnb[gc];
                v = fmaxf(v, 0.f);
            }
            if (CBF) ((u16*)Cv)[(size_t)gr * ldc + gc] = f2bf(v);
            else     ((float*)Cv)[(size_t)gr * ldc + gc] = v;
        }
    }
}

// ---------------- attention coefficients from bf16 features ----------------
// one wave per node; lane l covers flat channels 8l..8l+7 (head = l>>3)
__global__ __launch_bounds__(256) void gat_att(
    const u16* __restrict__ h,
    const float* __restrict__ att_src, const float* __restrict__ att_dst,
    float* __restrict__ aS, float* __restrict__ aD)
{
    int gid  = blockIdx.x * blockDim.x + threadIdx.x;
    int n    = gid >> 6;
    int lane = threadIdx.x & 63;
    if (n >= N_NODES) return;
    int head = lane >> 3;
    int ci   = (lane & 7) * 8;
    uint4 q = *(const uint4*)(h + (size_t)n * GOUT + lane * 8);
    float h0 = bf2f(q.x & 0xffff), h1 = bf2f(q.x >> 16);
    float h2 = bf2f(q.y & 0xffff), h3 = bf2f(q.y >> 16);
    float h4 = bf2f(q.z & 0xffff), h5 = bf2f(q.z >> 16);
    float h6 = bf2f(q.w & 0xffff), h7 = bf2f(q.w >> 16);
    const float* as = att_src + head * HID + ci;
    const float* ad = att_dst + head * HID + ci;
    float ss = h0*as[0] + h1*as[1] + h2*as[2] + h3*as[3]
             + h4*as[4] + h5*as[5] + h6*as[6] + h7*as[7];
    float dd = h0*ad[0] + h1*ad[1] + h2*ad[2] + h3*ad[3]
             + h4*ad[4] + h5*ad[5] + h6*ad[6] + h7*ad[7];
    ss += __shfl_xor(ss, 1); ss += __shfl_xor(ss, 2); ss += __shfl_xor(ss, 4);
    dd += __shfl_xor(dd, 1); dd += __shfl_xor(dd, 2); dd += __shfl_xor(dd, 4);
    if ((lane & 7) == 0) {
        aS[n * HEADS + head] = ss;
        aD[n * HEADS + head] = dd;
    }
}

// ---------------- CSR build ----------------
__global__ void k_init_counts(int* cnt) {
    int i = blockIdx.x * 256 + threadIdx.x;
    if (i < N_NODES) cnt[i] = 1;             // self-loop
}
__global__ void k_count(const int* __restrict__ dst, int* cnt) {
    int e = blockIdx.x * 256 + threadIdx.x;
    if (e < N_EDGES) atomicAdd(&cnt[dst[e]], 1);
}
__global__ void k_scan1(const int* __restrict__ cnt, int* __restrict__ off, int* __restrict__ bsum) {
    __shared__ int s[256];
    int b = blockIdx.x, t = threadIdx.x;
    s[t] = cnt[b * 256 + t]; __syncthreads();
    for (int d = 1; d < 256; d <<= 1) {
        int x = (t >= d) ? s[t - d] : 0;
        __syncthreads();
        s[t] += x;
        __syncthreads();
    }
    off[b * 256 + t + 1] = s[t];
    if (t == 255) bsum[b] = s[255];
}
__global__ void k_scan2(int* bsum) {
    __shared__ int s[256];
    int t = threadIdx.x;
    s[t] = bsum[t]; __syncthreads();
    for (int d = 1; d < 256; d <<= 1) {
        int x = (t >= d) ? s[t - d] : 0;
        __syncthreads();
        s[t] += x;
        __syncthreads();
    }
    bsum[t] = s[t];
}
__global__ void k_scan3(int* __restrict__ off, const int* __restrict__ bsum) {
    int b = blockIdx.x, t = threadIdx.x;
    if (b > 0) off[b * 256 + t + 1] += bsum[b - 1];
    if (b == 0 && t == 0) off[0] = 0;
}
__global__ void k_copy(const int* __restrict__ off, int* __restrict__ cur) {
    int i = blockIdx.x * 256 + threadIdx.x;
    if (i < N_NODES) cur[i] = off[i];
}
__global__ void k_fill(const int* __restrict__ esrc, const int* __restrict__ edst,
                       int* cur, int* __restrict__ srcs) {
    int i = blockIdx.x * 256 + threadIdx.x;
    if (i >= TOT_E) return;
    int s, d;
    if (i < N_EDGES) { s = esrc[i]; d = edst[i]; }
    else             { s = d = i - N_EDGES; }
    int p = atomicAdd(&cur[d], 1);
    srcs[p] = s;
}

// ---------------- GAT aggregation (bf16 features in/out) ----------------
// out[n,:] = ELU( sum_e alpha_e * h[src_e,:] + bias );  alpha = exp(lrelu)/sum
__global__ __launch_bounds__(256) void gat_aggregate(
    const u16* __restrict__ h, const float* __restrict__ aS, const float* __restrict__ aD,
    const int* __restrict__ off, const int* __restrict__ srcs,
    const float* __restrict__ bias, u16* __restrict__ out)
{
    int gid  = blockIdx.x * blockDim.x + threadIdx.x;
    int n    = gid >> 6;
    if (n >= N_NODES) return;
    int lane = threadIdx.x & 63;
    int head = lane >> 3;
    int o0 = off[n], o1 = off[n + 1];
    float aDn = aD[n * HEADS + head];
    float denom = 0.f;
    for (int o = o0; o < o1; ++o) {
        int s = srcs[o];
        float x = aS[s * HEADS + head] + aDn;
        x = x > 0.f ? x : 0.2f * x;
        denom += expf(x);
    }
    float inv = 1.f / (denom + 1e-16f);
    float acc[8] = {};
    for (int o = o0; o < o1; ++o) {
        int s = srcs[o];
        float x = aS[s * HEADS + head] + aDn;
        x = x > 0.f ? x : 0.2f * x;
        float alpha = expf(x) * inv;
        uint4 q = *(const uint4*)(h + (size_t)s * GOUT + lane * 8);
        acc[0] += alpha * bf2f(q.x & 0xffff); acc[1] += alpha * bf2f(q.x >> 16);
        acc[2] += alpha * bf2f(q.y & 0xffff); acc[3] += alpha * bf2f(q.y >> 16);
        acc[4] += alpha * bf2f(q.z & 0xffff); acc[5] += alpha * bf2f(q.z >> 16);
        acc[6] += alpha * bf2f(q.w & 0xffff); acc[7] += alpha * bf2f(q.w >> 16);
    }
    int c0 = lane * 8;
    float r[8];
    #pragma unroll
    for (int j = 0; j < 8; ++j) {
        float v = acc[j] + bias[c0 + j];
        r[j] = v > 0.f ? v : expm1f(v);
    }
    uint4 w;
    w.x = (u32)f2bf(r[0]) | ((u32)f2bf(r[1]) << 16);
    w.y = (u32)f2bf(r[2]) | ((u32)f2bf(r[3]) << 16);
    w.z = (u32)f2bf(r[4]) | ((u32)f2bf(r[5]) << 16);
    w.w = (u32)f2bf(r[6]) | ((u32)f2bf(r[7]) << 16);
    *(uint4*)(out + (size_t)n * GOUT + c0) = w;
}

// ---------------- global mean pool (batch sorted) into cbuf cols [0,512) ----------------
__global__ __launch_bounds__(256) void pool_kernel(
    const u16* __restrict__ x, const int* __restrict__ batch, float* __restrict__ cbuf)
{
    int b = blockIdx.x;
    int lo = 0, hi = N_NODES;
    while (lo < hi) { int mid = (lo + hi) >> 1; if (batch[mid] < b) lo = mid + 1; else hi = mid; }
    int start = lo;
    hi = N_NODES;
    while (lo < hi) { int mid = (lo + hi) >> 1; if (batch[mid] < b + 1) lo = mid + 1; else hi = mid; }
    int end = lo;
    int t = threadIdx.x;
    float s0 = 0.f, s1 = 0.f;
    for (int i = start; i < end; ++i) {
        s0 += bf2f(x[(size_t)i * GOUT + t]);
        s1 += bf2f(x[(size_t)i * GOUT + t + 256]);
    }
    float sc = 1.f / fmaxf((float)(end - start), 1.f);
    cbuf[(size_t)b * 1024 + t]       = s0 * sc;
    cbuf[(size_t)b * 1024 + t + 256] = s1 * sc;
}

// ---------------- final: out[b] = f2[b,:] . fW3 + fb3 ----------------
__global__ __launch_bounds__(64) void final_dot(
    const float* __restrict__ f2, const float* __restrict__ w,
    const float* __restrict__ b, float* __restrict__ out)
{
    int row = blockIdx.x, l = threadIdx.x;
    float v = f2[row * 128 + l] * w[l] + f2[row * 128 + 64 + l] * w[64 + l];
    v += __shfl_xor(v, 32); v += __shfl_xor(v, 16); v += __shfl_xor(v, 8);
    v += __shfl_xor(v, 4);  v += __shfl_xor(v, 2);  v += __shfl_xor(v, 1);
    if (l == 0) out[row] = v + b[0];
}

extern "C" void kernel_launch(void* const* d_in, const int* in_sizes, int n_in,
                              void* d_out, int out_size, void* d_ws, size_t ws_size,
                              hipStream_t stream)
{
    const float* x     = (const float*)d_in[0];
    const int*   ei    = (const int*)  d_in[1];
    const int*   batch = (const int*)  d_in[2];
    const float* x_gen = (const float*)d_in[3];
    const float* W1    = (const float*)d_in[4];
    const float* as1   = (const float*)d_in[5];
    const float* ad1   = (const float*)d_in[6];
    const float* b1    = (const float*)d_in[7];
    const float* W2    = (const float*)d_in[8];
    const float* as2   = (const float*)d_in[9];
    const float* ad2   = (const float*)d_in[10];
    const float* b2    = (const float*)d_in[11];
    const float* gW1   = (const float*)d_in[12];
    const float* gb1   = (const float*)d_in[13];
    const float* bng   = (const float*)d_in[14];
    const float* bnb   = (const float*)d_in[15];
    const float* bnm   = (const float*)d_in[16];
    const float* bnv   = (const float*)d_in[17];
    const float* gW2   = (const float*)d_in[18];
    const float* gb2   = (const float*)d_in[19];
    const float* fW1   = (const float*)d_in[20];
    const float* fb1   = (const float*)d_in[21];
    const float* fW2   = (const float*)d_in[22];
    const float* fb2   = (const float*)d_in[23];
    const float* fW3   = (const float*)d_in[24];
    const float* fb3   = (const float*)d_in[25];
    float* out = (float*)d_out;

    char* ws = (char*)d_ws;
    size_t off_b = 0;
    auto alloc = [&](size_t bytes) -> void* {
        void* p = ws + off_b;
        off_b += (bytes + 255) & ~(size_t)255;
        return p;
    };
    u16*   bufA    = (u16*)  alloc((size_t)N_NODES * GOUT * 2);   // bf16 features
    u16*   bufB    = (u16*)  alloc((size_t)N_NODES * GOUT * 2);   // bf16 features
    float* aSp     = (float*)alloc((size_t)N_NODES * HEADS * 4);  // reused per layer
    float* aDp     = (float*)alloc((size_t)N_NODES * HEADS * 4);
    int*   csr_off = (int*)  alloc((size_t)(N_NODES + 1) * 4);
    int*   csr_cur = (int*)  alloc((size_t)N_NODES * 4);
    int*   bsum    = (int*)  alloc(256 * 4);
    int*   csr_src = (int*)  alloc((size_t)TOT_E * 4);
    float* cbuf    = (float*)alloc((size_t)BATCHSZ * 1024 * 4);   // [g | z]
    float* z1b     = (float*)alloc((size_t)BATCHSZ * 128 * 4);
    float* f1b     = (float*)alloc((size_t)BATCHSZ * 256 * 4);
    float* f2b     = (float*)alloc((size_t)BATCHSZ * 128 * 4);

    // Guard: if workspace is too small, do nothing (clean wrong-answer beats a
    // memory fault; the resulting absmax tells us ws_size was the problem).
    if (off_b > ws_size) return;

    const int* esrc = ei;
    const int* edst = ei + N_EDGES;

    // ---- CSR by destination (self-loops included) ----
    k_init_counts<<<N_NODES / 256, 256, 0, stream>>>(csr_cur);
    k_count<<<N_EDGES / 256, 256, 0, stream>>>(edst, csr_cur);
    k_scan1<<<256, 256, 0, stream>>>(csr_cur, csr_off, bsum);
    k_scan2<<<1, 256, 0, stream>>>(bsum);
    k_scan3<<<256, 256, 0, stream>>>(csr_off, bsum);
    k_copy<<<N_NODES / 256, 256, 0, stream>>>(csr_off, csr_cur);
    k_fill<<<TOT_E / 256, 256, 0, stream>>>(esrc, edst, csr_cur, csr_src);

    // ---- GAT layer 1 ----
    dim3 gBig(N_NODES / 64, GOUT / 64);
    gemm_tile<0,0,1><<<gBig, 256, 0, stream>>>(x, W1, bufA, N_NODES, GOUT, F_IN, GOUT,
                                               nullptr, nullptr, nullptr, nullptr, nullptr);
    gat_att<<<N_NODES / 4, 256, 0, stream>>>(bufA, as1, ad1, aSp, aDp);
    gat_aggregate<<<N_NODES / 4, 256, 0, stream>>>(bufA, aSp, aDp, csr_off, csr_src, b1, bufB);

    // ---- GAT layer 2 ----
    gemm_tile<0,1,1><<<gBig, 256, 0, stream>>>(bufB, W2, bufA, N_NODES, GOUT, GOUT, GOUT,
                                               nullptr, nullptr, nullptr, nullptr, nullptr);
    gat_att<<<N_NODES / 4, 256, 0, stream>>>(bufA, as2, ad2, aSp, aDp);
    gat_aggregate<<<N_NODES / 4, 256, 0, stream>>>(bufA, aSp, aDp, csr_off, csr_src, b2, bufB);

    // ---- pool into cbuf[:, 0:512) ----
    pool_kernel<<<BATCHSZ, 256, 0, stream>>>(bufB, batch, cbuf);

    // ---- genomic encoder ----
    dim3 gG1((BATCHSZ + 63) / 64, (128 + 63) / 64);
    gemm_tile<3,0,0><<<gG1, 256, 0, stream>>>(x_gen, gW1, z1b, BATCHSZ, 128, GENES, 128,
                                              gb1, bng, bnb, bnm, bnv);
    dim3 gG2(BATCHSZ / 64, GOUT / 64);
    gemm_tile<2,0,0><<<gG2, 256, 0, stream>>>(z1b, gW2, cbuf + 512, BATCHSZ, GOUT, 128, 1024,
                                              gb2, nullptr, nullptr, nullptr, nullptr);

    // ---- fusion MLP ----
    dim3 gF1(BATCHSZ / 64, 256 / 64);
    gemm_tile<2,0,0><<<gF1, 256, 0, stream>>>(cbuf, fW1, f1b, BATCHSZ, 256, 1024, 256,
                                              fb1, nullptr, nullptr, nullptr, nullptr);
    dim3 gF2(BATCHSZ / 64, 128 / 64);
    gemm_tile<2,0,0><<<gF2, 256, 0, stream>>>(f1b, fW2, f2b, BATCHSZ, 128, 256, 128,
                                              fb2, nullptr, nullptr, nullptr, nullptr);
    final_dot<<<BATCHSZ, 64, 0, stream>>>(f2b, fW3, fb3, out);
}

// Round 6
// 918.474 us; speedup vs baseline: 1.9969x; 1.9969x over previous
//
#include <hip/hip_runtime.h>
#include <hip/hip_bf16.h>
#include <math.h>

#define N_NODES 65536
#define N_EDGES 262144
#define BATCHSZ 2048
#define F_IN    78
#define K1PAD   96
#define GENES   735
#define GOUT    512
#define HEADS   8
#define HID     64
#define TOT_E   (N_EDGES + N_NODES)   // 327680

typedef unsigned short u16;
typedef unsigned int   u32;
typedef __attribute__((ext_vector_type(4))) float f32x4;
typedef __attribute__((ext_vector_type(8))) short bf16x8;

__device__ __forceinline__ float bf2f(u32 h) {
    u32 u = h << 16;
    return __uint_as_float(u);
}
__device__ __forceinline__ u16 f2bf(float f) {
    u32 u = __float_as_uint(f);
    u32 r = (u + 0x7FFFu + ((u >> 16) & 1u)) >> 16;   // round-to-nearest-even
    return (u16)r;
}

// ================= MFMA bf16 GEMM =================
// C[M,N]bf16 = A[M,K]bf16 @ BT[N,K]bf16^T.  M%128==0, N%128==0, K%32==0.
// Block 256 thr = 4 waves (2x2), each wave 64x64 via 4x4 frags of 16x16x32.
// LDS rows padded to 40 bf16 (80B) -> <=2-way bank aliasing on b128 reads (free).
__global__ __launch_bounds__(256) void gemm_mfma(
    const u16* __restrict__ A, const u16* __restrict__ BT, u16* __restrict__ C,
    int M, int N, int K, int ldc)
{
    __shared__ u16 Al[128 * 40];
    __shared__ u16 Bl[128 * 40];
    int t    = threadIdx.x;
    int wid  = t >> 6, lane = t & 63;
    int wm   = wid >> 1, wn = wid & 1;
    int bm   = blockIdx.x * 128, bn = blockIdx.y * 128;

    f32x4 acc[4][4] = {};

    for (int k0 = 0; k0 < K; k0 += 32) {
        #pragma unroll
        for (int i = 0; i < 2; ++i) {
            int flat = t + i * 256;          // 0..511
            int row  = flat >> 2, slot = flat & 3;
            uint4 va = *(const uint4*)(A  + (size_t)(bm + row) * K + k0 + slot * 8);
            *(uint4*)(Al + row * 40 + slot * 8) = va;
            uint4 vb = *(const uint4*)(BT + (size_t)(bn + row) * K + k0 + slot * 8);
            *(uint4*)(Bl + row * 40 + slot * 8) = vb;
        }
        __syncthreads();
        bf16x8 af[4], bfr[4];
        int r0 = wm * 64 + (lane & 15);
        int c0 = wn * 64 + (lane & 15);
        int kk = (lane >> 4) * 8;
        #pragma unroll
        for (int m = 0; m < 4; ++m)
            af[m] = *(const bf16x8*)(Al + (r0 + m * 16) * 40 + kk);
        #pragma unroll
        for (int n = 0; n < 4; ++n)
            bfr[n] = *(const bf16x8*)(Bl + (c0 + n * 16) * 40 + kk);
        #pragma unroll
        for (int m = 0; m < 4; ++m)
            #pragma unroll
            for (int n = 0; n < 4; ++n)
                acc[m][n] = __builtin_amdgcn_mfma_f32_16x16x32_bf16(af[m], bfr[n], acc[m][n], 0, 0, 0);
        __syncthreads();
    }
    int rbase = bm + wm * 64 + (lane >> 4) * 4;
    int cbase = bn + wn * 64 + (lane & 15);
    #pragma unroll
    for (int m = 0; m < 4; ++m)
        #pragma unroll
        for (int n = 0; n < 4; ++n) {
            int col = cbase + n * 16;
            #pragma unroll
            for (int j = 0; j < 4; ++j) {
                int row = rbase + m * 16 + j;
                C[(size_t)row * ldc + col] = f2bf(acc[m][n][j]);
            }
        }
}

// ---- weight/input conversion: f32 -> bf16 (optionally transposed / K-padded) ----
__global__ void conv_x_pad(const float* __restrict__ x, u16* __restrict__ xb) {
    int i = blockIdx.x * 256 + threadIdx.x;          // over N_NODES*K1PAD
    int row = i / K1PAD, col = i - row * K1PAD;
    xb[i] = (col < F_IN) ? f2bf(x[(size_t)row * F_IN + col]) : (u16)0;
}
__global__ void conv_w1t(const float* __restrict__ W, u16* __restrict__ WT) {
    int i = blockIdx.x * 256 + threadIdx.x;          // over GOUT*K1PAD
    int n = i / K1PAD, k = i - n * K1PAD;
    WT[i] = (k < F_IN) ? f2bf(W[(size_t)k * GOUT + n]) : (u16)0;
}
__global__ void conv_w2t(const float* __restrict__ W, u16* __restrict__ WT) {
    int i = blockIdx.x * 256 + threadIdx.x;          // over GOUT*GOUT
    int n = i >> 9, k = i & 511;
    WT[i] = f2bf(W[(size_t)k * GOUT + n]);
}

// ---------------- tiled GEMM, f32 compute (small MLP-side GEMMs) ----------------
// EPI: 2=relu(acc+bias), 3=bn-relu
template<int EPI>
__global__ __launch_bounds__(256) void gemm_tile(
    const float* __restrict__ A, const float* __restrict__ B, float* __restrict__ C,
    int M, int N, int K, int ldc,
    const float* __restrict__ bias,
    const float* __restrict__ bng, const float* __restrict__ bnb,
    const float* __restrict__ bnm, const float* __restrict__ bnv)
{
    __shared__ float As[64][33];
    __shared__ float Bs[32][64];
    int t  = threadIdx.x;
    int bm = blockIdx.x * 64, bn = blockIdx.y * 64;
    int ty = t >> 4, tx = t & 15;
    float acc[4][4] = {};
    for (int k0 = 0; k0 < K; k0 += 32) {
        #pragma unroll
        for (int i = 0; i < 8; ++i) {
            int idx = t + i * 256;
            int r = idx >> 5, kk = idx & 31;
            int gr = bm + r, gk = k0 + kk;
            As[r][kk] = (gr < M && gk < K) ? A[(size_t)gr * K + gk] : 0.f;
        }
        #pragma unroll
        for (int i = 0; i < 8; ++i) {
            int idx = t + i * 256;
            int kk = idx >> 6, c = idx & 63;
            int gk = k0 + kk, gc = bn + c;
            Bs[kk][c] = (gk < K && gc < N) ? B[(size_t)gk * N + gc] : 0.f;
        }
        __syncthreads();
        #pragma unroll
        for (int k = 0; k < 32; ++k) {
            float a0 = As[ty*4+0][k], a1 = As[ty*4+1][k];
            float a2 = As[ty*4+2][k], a3 = As[ty*4+3][k];
            float4 b = *(const float4*)&Bs[k][tx*4];
            acc[0][0] += a0*b.x; acc[0][1] += a0*b.y; acc[0][2] += a0*b.z; acc[0][3] += a0*b.w;
            acc[1][0] += a1*b.x; acc[1][1] += a1*b.y; acc[1][2] += a1*b.z; acc[1][3] += a1*b.w;
            acc[2][0] += a2*b.x; acc[2][1] += a2*b.y; acc[2][2] += a2*b.z; acc[2][3] += a2*b.w;
            acc[3][0] += a3*b.x; acc[3][1] += a3*b.y; acc[3][2] += a3*b.z; acc[3][3] += a3*b.w;
        }
        __syncthreads();
    }
    #pragma unroll
    for (int i = 0; i < 4; ++i) {
        int gr = bm + ty*4 + i;
        if (gr >= M) continue;
        #pragma unroll
        for (int j = 0; j < 4; ++j) {
            int gc = bn + tx*4 + j;
            if (gc >= N) continue;
            float v = acc[i][j];
            if (EPI == 2) { v += bias[gc]; v = fmaxf(v, 0.f); }
            if (EPI == 3) {
                float s = bng[gc] * rsqrtf(bnv[gc] + 1e-5f);
                v = (v + bias[gc] - bnm[gc]) * s + bnb[gc];
                v = fmaxf(v, 0.f);
            }
            C[(size_t)gr * ldc + gc] = v;
        }
    }
}

// ---------------- attention coefficients from bf16 features ----------------
__global__ __launch_bounds__(256) void gat_att(
    const u16* __restrict__ h,
    const float* __restrict__ att_src, const float* __restrict__ att_dst,
    float* __restrict__ aS, float* __restrict__ aD)
{
    int gid  = blockIdx.x * blockDim.x + threadIdx.x;
    int n    = gid >> 6;
    int lane = threadIdx.x & 63;
    if (n >= N_NODES) return;
    int head = lane >> 3;
    int ci   = (lane & 7) * 8;
    uint4 q = *(const uint4*)(h + (size_t)n * GOUT + lane * 8);
    float h0 = bf2f(q.x & 0xffff), h1 = bf2f(q.x >> 16);
    float h2 = bf2f(q.y & 0xffff), h3 = bf2f(q.y >> 16);
    float h4 = bf2f(q.z & 0xffff), h5 = bf2f(q.z >> 16);
    float h6 = bf2f(q.w & 0xffff), h7 = bf2f(q.w >> 16);
    const float* as = att_src + head * HID + ci;
    const float* ad = att_dst + head * HID + ci;
    float ss = h0*as[0] + h1*as[1] + h2*as[2] + h3*as[3]
             + h4*as[4] + h5*as[5] + h6*as[6] + h7*as[7];
    float dd = h0*ad[0] + h1*ad[1] + h2*ad[2] + h3*ad[3]
             + h4*ad[4] + h5*ad[5] + h6*ad[6] + h7*ad[7];
    ss += __shfl_xor(ss, 1); ss += __shfl_xor(ss, 2); ss += __shfl_xor(ss, 4);
    dd += __shfl_xor(dd, 1); dd += __shfl_xor(dd, 2); dd += __shfl_xor(dd, 4);
    if ((lane & 7) == 0) {
        aS[n * HEADS + head] = ss;
        aD[n * HEADS + head] = dd;
    }
}

// ---------------- CSR build ----------------
__global__ void k_init_counts(int* cnt) {
    int i = blockIdx.x * 256 + threadIdx.x;
    if (i < N_NODES) cnt[i] = 1;             // self-loop
}
__global__ void k_count(const int* __restrict__ dst, int* cnt) {
    int e = blockIdx.x * 256 + threadIdx.x;
    if (e < N_EDGES) atomicAdd(&cnt[dst[e]], 1);
}
__global__ void k_scan1(const int* __restrict__ cnt, int* __restrict__ off, int* __restrict__ bsum) {
    __shared__ int s[256];
    int b = blockIdx.x, t = threadIdx.x;
    s[t] = cnt[b * 256 + t]; __syncthreads();
    for (int d = 1; d < 256; d <<= 1) {
        int x = (t >= d) ? s[t - d] : 0;
        __syncthreads();
        s[t] += x;
        __syncthreads();
    }
    off[b * 256 + t + 1] = s[t];
    if (t == 255) bsum[b] = s[255];
}
__global__ void k_scan2(int* bsum) {
    __shared__ int s[256];
    int t = threadIdx.x;
    s[t] = bsum[t]; __syncthreads();
    for (int d = 1; d < 256; d <<= 1) {
        int x = (t >= d) ? s[t - d] : 0;
        __syncthreads();
        s[t] += x;
        __syncthreads();
    }
    bsum[t] = s[t];
}
__global__ void k_scan3(int* __restrict__ off, const int* __restrict__ bsum) {
    int b = blockIdx.x, t = threadIdx.x;
    if (b > 0) off[b * 256 + t + 1] += bsum[b - 1];
    if (b == 0 && t == 0) off[0] = 0;
}
__global__ void k_copy(const int* __restrict__ off, int* __restrict__ cur) {
    int i = blockIdx.x * 256 + threadIdx.x;
    if (i < N_NODES) cur[i] = off[i];
}
__global__ void k_fill(const int* __restrict__ esrc, const int* __restrict__ edst,
                       int* cur, int* __restrict__ srcs) {
    int i = blockIdx.x * 256 + threadIdx.x;
    if (i >= TOT_E) return;
    int s, d;
    if (i < N_EDGES) { s = esrc[i]; d = edst[i]; }
    else             { s = d = i - N_EDGES; }
    int p = atomicAdd(&cur[d], 1);
    srcs[p] = s;
}

// ---------------- GAT aggregation (bf16 features in/out) ----------------
__global__ __launch_bounds__(256) void gat_aggregate(
    const u16* __restrict__ h, const float* __restrict__ aS, const float* __restrict__ aD,
    const int* __restrict__ off, const int* __restrict__ srcs,
    const float* __restrict__ bias, u16* __restrict__ out)
{
    int gid  = blockIdx.x * blockDim.x + threadIdx.x;
    int n    = gid >> 6;
    if (n >= N_NODES) return;
    int lane = threadIdx.x & 63;
    int head = lane >> 3;
    int o0 = off[n], o1 = off[n + 1];
    float aDn = aD[n * HEADS + head];
    float denom = 0.f;
    for (int o = o0; o < o1; ++o) {
        int s = srcs[o];
        float x = aS[s * HEADS + head] + aDn;
        x = x > 0.f ? x : 0.2f * x;
        denom += expf(x);
    }
    float inv = 1.f / (denom + 1e-16f);
    float acc[8] = {};
    for (int o = o0; o < o1; ++o) {
        int s = srcs[o];
        float x = aS[s * HEADS + head] + aDn;
        x = x > 0.f ? x : 0.2f * x;
        float alpha = expf(x) * inv;
        uint4 q = *(const uint4*)(h + (size_t)s * GOUT + lane * 8);
        acc[0] += alpha * bf2f(q.x & 0xffff); acc[1] += alpha * bf2f(q.x >> 16);
        acc[2] += alpha * bf2f(q.y & 0xffff); acc[3] += alpha * bf2f(q.y >> 16);
        acc[4] += alpha * bf2f(q.z & 0xffff); acc[5] += alpha * bf2f(q.z >> 16);
        acc[6] += alpha * bf2f(q.w & 0xffff); acc[7] += alpha * bf2f(q.w >> 16);
    }
    int c0 = lane * 8;
    float r[8];
    #pragma unroll
    for (int j = 0; j < 8; ++j) {
        float v = acc[j] + bias[c0 + j];
        r[j] = v > 0.f ? v : expm1f(v);
    }
    uint4 w;
    w.x = (u32)f2bf(r[0]) | ((u32)f2bf(r[1]) << 16);
    w.y = (u32)f2bf(r[2]) | ((u32)f2bf(r[3]) << 16);
    w.z = (u32)f2bf(r[4]) | ((u32)f2bf(r[5]) << 16);
    w.w = (u32)f2bf(r[6]) | ((u32)f2bf(r[7]) << 16);
    *(uint4*)(out + (size_t)n * GOUT + c0) = w;
}

// ---------------- global mean pool ----------------
__global__ __launch_bounds__(256) void pool_kernel(
    const u16* __restrict__ x, const int* __restrict__ batch, float* __restrict__ cbuf)
{
    int b = blockIdx.x;
    int lo = 0, hi = N_NODES;
    while (lo < hi) { int mid = (lo + hi) >> 1; if (batch[mid] < b) lo = mid + 1; else hi = mid; }
    int start = lo;
    hi = N_NODES;
    while (lo < hi) { int mid = (lo + hi) >> 1; if (batch[mid] < b + 1) lo = mid + 1; else hi = mid; }
    int end = lo;
    int t = threadIdx.x;
    float s0 = 0.f, s1 = 0.f;
    for (int i = start; i < end; ++i) {
        s0 += bf2f(x[(size_t)i * GOUT + t]);
        s1 += bf2f(x[(size_t)i * GOUT + t + 256]);
    }
    float sc = 1.f / fmaxf((float)(end - start), 1.f);
    cbuf[(size_t)b * 1024 + t]       = s0 * sc;
    cbuf[(size_t)b * 1024 + t + 256] = s1 * sc;
}

// ---------------- final dot ----------------
__global__ __launch_bounds__(64) void final_dot(
    const float* __restrict__ f2, const float* __restrict__ w,
    const float* __restrict__ b, float* __restrict__ out)
{
    int row = blockIdx.x, l = threadIdx.x;
    float v = f2[row * 128 + l] * w[l] + f2[row * 128 + 64 + l] * w[64 + l];
    v += __shfl_xor(v, 32); v += __shfl_xor(v, 16); v += __shfl_xor(v, 8);
    v += __shfl_xor(v, 4);  v += __shfl_xor(v, 2);  v += __shfl_xor(v, 1);
    if (l == 0) out[row] = v + b[0];
}

extern "C" void kernel_launch(void* const* d_in, const int* in_sizes, int n_in,
                              void* d_out, int out_size, void* d_ws, size_t ws_size,
                              hipStream_t stream)
{
    const float* x     = (const float*)d_in[0];
    const int*   ei    = (const int*)  d_in[1];
    const int*   batch = (const int*)  d_in[2];
    const float* x_gen = (const float*)d_in[3];
    const float* W1    = (const float*)d_in[4];
    const float* as1   = (const float*)d_in[5];
    const float* ad1   = (const float*)d_in[6];
    const float* b1    = (const float*)d_in[7];
    const float* W2    = (const float*)d_in[8];
    const float* as2   = (const float*)d_in[9];
    const float* ad2   = (const float*)d_in[10];
    const float* b2    = (const float*)d_in[11];
    const float* gW1   = (const float*)d_in[12];
    const float* gb1   = (const float*)d_in[13];
    const float* bng   = (const float*)d_in[14];
    const float* bnb   = (const float*)d_in[15];
    const float* bnm   = (const float*)d_in[16];
    const float* bnv   = (const float*)d_in[17];
    const float* gW2   = (const float*)d_in[18];
    const float* gb2   = (const float*)d_in[19];
    const float* fW1   = (const float*)d_in[20];
    const float* fb1   = (const float*)d_in[21];
    const float* fW2   = (const float*)d_in[22];
    const float* fb2   = (const float*)d_in[23];
    const float* fW3   = (const float*)d_in[24];
    const float* fb3   = (const float*)d_in[25];
    float* out = (float*)d_out;

    char* ws = (char*)d_ws;
    size_t off_b = 0;
    auto alloc = [&](size_t bytes) -> void* {
        void* p = ws + off_b;
        off_b += (bytes + 255) & ~(size_t)255;
        return p;
    };
    u16*   bufA    = (u16*)  alloc((size_t)N_NODES * GOUT * 2);   // bf16 features
    u16*   bufB    = (u16*)  alloc((size_t)N_NODES * GOUT * 2);   // bf16 features
    u16*   xb      = (u16*)  alloc((size_t)N_NODES * K1PAD * 2);  // x bf16, K-padded
    u16*   w1t     = (u16*)  alloc((size_t)GOUT * K1PAD * 2);     // W1^T bf16 padded
    u16*   w2t     = (u16*)  alloc((size_t)GOUT * GOUT * 2);      // W2^T bf16
    float* aSp     = (float*)alloc((size_t)N_NODES * HEADS * 4);
    float* aDp     = (float*)alloc((size_t)N_NODES * HEADS * 4);
    int*   csr_off = (int*)  alloc((size_t)(N_NODES + 1) * 4);
    int*   csr_cur = (int*)  alloc((size_t)N_NODES * 4);
    int*   bsum    = (int*)  alloc(256 * 4);
    int*   csr_src = (int*)  alloc((size_t)TOT_E * 4);
    float* cbuf    = (float*)alloc((size_t)BATCHSZ * 1024 * 4);   // [g | z]
    float* z1b     = (float*)alloc((size_t)BATCHSZ * 128 * 4);
    float* f1b     = (float*)alloc((size_t)BATCHSZ * 256 * 4);
    float* f2b     = (float*)alloc((size_t)BATCHSZ * 128 * 4);

    if (off_b > ws_size) return;   // clean no-op beats a memory fault

    const int* esrc = ei;
    const int* edst = ei + N_EDGES;

    // ---- conversions (bf16 weights/inputs for MFMA) ----
    conv_x_pad<<<(N_NODES * K1PAD) / 256, 256, 0, stream>>>(x, xb);
    conv_w1t<<<(GOUT * K1PAD) / 256, 256, 0, stream>>>(W1, w1t);
    conv_w2t<<<(GOUT * GOUT) / 256, 256, 0, stream>>>(W2, w2t);

    // ---- CSR by destination ----
    k_init_counts<<<N_NODES / 256, 256, 0, stream>>>(csr_cur);
    k_count<<<N_EDGES / 256, 256, 0, stream>>>(edst, csr_cur);
    k_scan1<<<256, 256, 0, stream>>>(csr_cur, csr_off, bsum);
    k_scan2<<<1, 256, 0, stream>>>(bsum);
    k_scan3<<<256, 256, 0, stream>>>(csr_off, bsum);
    k_copy<<<N_NODES / 256, 256, 0, stream>>>(csr_off, csr_cur);
    k_fill<<<TOT_E / 256, 256, 0, stream>>>(esrc, edst, csr_cur, csr_src);

    // ---- GAT layer 1 (MFMA) ----
    dim3 gMF(N_NODES / 128, GOUT / 128);
    gemm_mfma<<<gMF, 256, 0, stream>>>(xb, w1t, bufA, N_NODES, GOUT, K1PAD, GOUT);
    gat_att<<<N_NODES / 4, 256, 0, stream>>>(bufA, as1, ad1, aSp, aDp);
    gat_aggregate<<<N_NODES / 4, 256, 0, stream>>>(bufA, aSp, aDp, csr_off, csr_src, b1, bufB);

    // ---- GAT layer 2 (MFMA) ----
    gemm_mfma<<<gMF, 256, 0, stream>>>(bufB, w2t, bufA, N_NODES, GOUT, GOUT, GOUT);
    gat_att<<<N_NODES / 4, 256, 0, stream>>>(bufA, as2, ad2, aSp, aDp);
    gat_aggregate<<<N_NODES / 4, 256, 0, stream>>>(bufA, aSp, aDp, csr_off, csr_src, b2, bufB);

    // ---- pool ----
    pool_kernel<<<BATCHSZ, 256, 0, stream>>>(bufB, batch, cbuf);

    // ---- genomic encoder (f32) ----
    dim3 gG1((BATCHSZ + 63) / 64, (128 + 63) / 64);
    gemm_tile<3><<<gG1, 256, 0, stream>>>(x_gen, gW1, z1b, BATCHSZ, 128, GENES, 128,
                                          gb1, bng, bnb, bnm, bnv);
    dim3 gG2(BATCHSZ / 64, GOUT / 64);
    gemm_tile<2><<<gG2, 256, 0, stream>>>(z1b, gW2, cbuf + 512, BATCHSZ, GOUT, 128, 1024,
                                          gb2, nullptr, nullptr, nullptr, nullptr);

    // ---- fusion MLP (f32) ----
    dim3 gF1(BATCHSZ / 64, 256 / 64);
    gemm_tile<2><<<gF1, 256, 0, stream>>>(cbuf, fW1, f1b, BATCHSZ, 256, 1024, 256,
                                          fb1, nullptr, nullptr, nullptr, nullptr);
    dim3 gF2(BATCHSZ / 64, 128 / 64);
    gemm_tile<2><<<gF2, 256, 0, stream>>>(f1b, fW2, f2b, BATCHSZ, 128, 256, 128,
                                          fb2, nullptr, nullptr, nullptr, nullptr);
    final_dot<<<BATCHSZ, 64, 0, stream>>>(f2b, fW3, fb3, out);
}

// Round 7
// 732.362 us; speedup vs baseline: 2.5043x; 1.2541x over previous
//
#include <hip/hip_runtime.h>
#include <hip/hip_bf16.h>
#include <math.h>

#define N_NODES 65536
#define N_EDGES 262144
#define BATCHSZ 2048
#define F_IN    78
#define K1PAD   96
#define GENES   735
#define GOUT    512
#define HEADS   8
#define HID     64
#define TOT_E   (N_EDGES + N_NODES)   // 327680

typedef unsigned short u16;
typedef unsigned int   u32;
typedef __attribute__((ext_vector_type(4))) float f32x4;
typedef __attribute__((ext_vector_type(8))) short bf16x8;

__device__ __forceinline__ float bf2f(u32 h) {
    u32 u = h << 16;
    return __uint_as_float(u);
}
__device__ __forceinline__ u16 f2bf(float f) {
    u32 u = __float_as_uint(f);
    u32 r = (u + 0x7FFFu + ((u >> 16) & 1u)) >> 16;   // round-to-nearest-even
    return (u16)r;
}

// ================= MFMA bf16 GEMM (node-feature GEMMs) =================
// C[M,N]bf16 = A[M,K]bf16 @ BT[N,K]bf16^T.  M%128==0, N%128==0, K%32==0.
// Block 256 thr = 4 waves (2x2), each wave 64x64 via 4x4 frags of 16x16x32.
// LDS rows padded to 40 bf16 (80B) -> <=2-way bank aliasing on b128 reads (free).
__global__ __launch_bounds__(256) void gemm_mfma(
    const u16* __restrict__ A, const u16* __restrict__ BT, u16* __restrict__ C,
    int M, int N, int K, int ldc)
{
    __shared__ u16 Al[128 * 40];
    __shared__ u16 Bl[128 * 40];
    int t    = threadIdx.x;
    int wid  = t >> 6, lane = t & 63;
    int wm   = wid >> 1, wn = wid & 1;
    int bm   = blockIdx.x * 128, bn = blockIdx.y * 128;

    f32x4 acc[4][4] = {};

    for (int k0 = 0; k0 < K; k0 += 32) {
        #pragma unroll
        for (int i = 0; i < 2; ++i) {
            int flat = t + i * 256;          // 0..511
            int row  = flat >> 2, slot = flat & 3;
            uint4 va = *(const uint4*)(A  + (size_t)(bm + row) * K + k0 + slot * 8);
            *(uint4*)(Al + row * 40 + slot * 8) = va;
            uint4 vb = *(const uint4*)(BT + (size_t)(bn + row) * K + k0 + slot * 8);
            *(uint4*)(Bl + row * 40 + slot * 8) = vb;
        }
        __syncthreads();
        bf16x8 af[4], bfr[4];
        int r0 = wm * 64 + (lane & 15);
        int c0 = wn * 64 + (lane & 15);
        int kk = (lane >> 4) * 8;
        #pragma unroll
        for (int m = 0; m < 4; ++m)
            af[m] = *(const bf16x8*)(Al + (r0 + m * 16) * 40 + kk);
        #pragma unroll
        for (int n = 0; n < 4; ++n)
            bfr[n] = *(const bf16x8*)(Bl + (c0 + n * 16) * 40 + kk);
        #pragma unroll
        for (int m = 0; m < 4; ++m)
            #pragma unroll
            for (int n = 0; n < 4; ++n)
                acc[m][n] = __builtin_amdgcn_mfma_f32_16x16x32_bf16(af[m], bfr[n], acc[m][n], 0, 0, 0);
        __syncthreads();
    }
    int rbase = bm + wm * 64 + (lane >> 4) * 4;
    int cbase = bn + wn * 64 + (lane & 15);
    #pragma unroll
    for (int m = 0; m < 4; ++m)
        #pragma unroll
        for (int n = 0; n < 4; ++n) {
            int col = cbase + n * 16;
            #pragma unroll
            for (int j = 0; j < 4; ++j) {
                int row = rbase + m * 16 + j;
                C[(size_t)row * ldc + col] = f2bf(acc[m][n][j]);
            }
        }
}

// ---- weight/input conversion: f32 -> bf16 (optionally transposed / K-padded) ----
__global__ void conv_x_pad(const float* __restrict__ x, u16* __restrict__ xb) {
    int i = blockIdx.x * 256 + threadIdx.x;          // over N_NODES*K1PAD
    int row = i / K1PAD, col = i - row * K1PAD;
    xb[i] = (col < F_IN) ? f2bf(x[(size_t)row * F_IN + col]) : (u16)0;
}
__global__ void conv_w1t(const float* __restrict__ W, u16* __restrict__ WT) {
    int i = blockIdx.x * 256 + threadIdx.x;          // over GOUT*K1PAD
    int n = i / K1PAD, k = i - n * K1PAD;
    WT[i] = (k < F_IN) ? f2bf(W[(size_t)k * GOUT + n]) : (u16)0;
}
__global__ void conv_w2t(const float* __restrict__ W, u16* __restrict__ WT) {
    int i = blockIdx.x * 256 + threadIdx.x;          // over GOUT*GOUT
    int n = i >> 9, k = i & 511;
    WT[i] = f2bf(W[(size_t)k * GOUT + n]);
}

// ---------------- small-GEMM: 32x32 tile, f32, high grid parallelism ----------------
// For M=2048-by-small-N MLP GEMMs (occupancy-bound, not FLOP-bound).
// EPI: 2=relu(acc+bias), 3=bn-relu
template<int EPI>
__global__ __launch_bounds__(256) void gemm_small(
    const float* __restrict__ A, const float* __restrict__ B, float* __restrict__ C,
    int M, int N, int K, int ldc,
    const float* __restrict__ bias,
    const float* __restrict__ bng, const float* __restrict__ bnb,
    const float* __restrict__ bnm, const float* __restrict__ bnv)
{
    __shared__ float As[32][33];
    __shared__ float Bs[32][33];
    int t  = threadIdx.x;
    int bm = blockIdx.x * 32, bn = blockIdx.y * 32;
    int ty = t >> 4, tx = t & 15;          // 16x16 threads, 2x2 each
    float acc[2][2] = {};
    for (int k0 = 0; k0 < K; k0 += 32) {
        #pragma unroll
        for (int i = 0; i < 4; ++i) {
            int idx = t + i * 256;
            int r = idx >> 5, kk = idx & 31;     // consecutive t -> consecutive kk (coalesced)
            int gr = bm + r, gk = k0 + kk;
            As[r][kk] = (gr < M && gk < K) ? A[(size_t)gr * K + gk] : 0.f;
            int kr = idx >> 5, c = idx & 31;
            int gk2 = k0 + kr, gc = bn + c;
            Bs[kr][c] = (gk2 < K && gc < N) ? B[(size_t)gk2 * N + gc] : 0.f;
        }
        __syncthreads();
        #pragma unroll
        for (int k = 0; k < 32; ++k) {
            float a0 = As[ty*2+0][k], a1 = As[ty*2+1][k];
            float b0 = Bs[k][tx*2+0], b1 = Bs[k][tx*2+1];
            acc[0][0] += a0*b0; acc[0][1] += a0*b1;
            acc[1][0] += a1*b0; acc[1][1] += a1*b1;
        }
        __syncthreads();
    }
    #pragma unroll
    for (int i = 0; i < 2; ++i) {
        int gr = bm + ty*2 + i;
        if (gr >= M) continue;
        #pragma unroll
        for (int j = 0; j < 2; ++j) {
            int gc = bn + tx*2 + j;
            if (gc >= N) continue;
            float v = acc[i][j];
            if (EPI == 2) { v += bias[gc]; v = fmaxf(v, 0.f); }
            if (EPI == 3) {
                float s = bng[gc] * rsqrtf(bnv[gc] + 1e-5f);
                v = (v + bias[gc] - bnm[gc]) * s + bnb[gc];
                v = fmaxf(v, 0.f);
            }
            C[(size_t)gr * ldc + gc] = v;
        }
    }
}

// ---------------- attention coefficients from bf16 features ----------------
__global__ __launch_bounds__(256) void gat_att(
    const u16* __restrict__ h,
    const float* __restrict__ att_src, const float* __restrict__ att_dst,
    float* __restrict__ aS, float* __restrict__ aD)
{
    int gid  = blockIdx.x * blockDim.x + threadIdx.x;
    int n    = gid >> 6;
    int lane = threadIdx.x & 63;
    if (n >= N_NODES) return;
    int head = lane >> 3;
    int ci   = (lane & 7) * 8;
    uint4 q = *(const uint4*)(h + (size_t)n * GOUT + lane * 8);
    float h0 = bf2f(q.x & 0xffff), h1 = bf2f(q.x >> 16);
    float h2 = bf2f(q.y & 0xffff), h3 = bf2f(q.y >> 16);
    float h4 = bf2f(q.z & 0xffff), h5 = bf2f(q.z >> 16);
    float h6 = bf2f(q.w & 0xffff), h7 = bf2f(q.w >> 16);
    const float* as = att_src + head * HID + ci;
    const float* ad = att_dst + head * HID + ci;
    float ss = h0*as[0] + h1*as[1] + h2*as[2] + h3*as[3]
             + h4*as[4] + h5*as[5] + h6*as[6] + h7*as[7];
    float dd = h0*ad[0] + h1*ad[1] + h2*ad[2] + h3*ad[3]
             + h4*ad[4] + h5*ad[5] + h6*ad[6] + h7*ad[7];
    ss += __shfl_xor(ss, 1); ss += __shfl_xor(ss, 2); ss += __shfl_xor(ss, 4);
    dd += __shfl_xor(dd, 1); dd += __shfl_xor(dd, 2); dd += __shfl_xor(dd, 4);
    if ((lane & 7) == 0) {
        aS[n * HEADS + head] = ss;
        aD[n * HEADS + head] = dd;
    }
}

// ---------------- CSR build ----------------
__global__ void k_init_counts(int* cnt) {
    int i = blockIdx.x * 256 + threadIdx.x;
    if (i < N_NODES) cnt[i] = 1;             // self-loop
}
__global__ void k_count(const int* __restrict__ dst, int* cnt) {
    int e = blockIdx.x * 256 + threadIdx.x;
    if (e < N_EDGES) atomicAdd(&cnt[dst[e]], 1);
}
__global__ void k_scan1(const int* __restrict__ cnt, int* __restrict__ off, int* __restrict__ bsum) {
    __shared__ int s[256];
    int b = blockIdx.x, t = threadIdx.x;
    s[t] = cnt[b * 256 + t]; __syncthreads();
    for (int d = 1; d < 256; d <<= 1) {
        int x = (t >= d) ? s[t - d] : 0;
        __syncthreads();
        s[t] += x;
        __syncthreads();
    }
    off[b * 256 + t + 1] = s[t];
    if (t == 255) bsum[b] = s[255];
}
__global__ void k_scan2(int* bsum) {
    __shared__ int s[256];
    int t = threadIdx.x;
    s[t] = bsum[t]; __syncthreads();
    for (int d = 1; d < 256; d <<= 1) {
        int x = (t >= d) ? s[t - d] : 0;
        __syncthreads();
        s[t] += x;
        __syncthreads();
    }
    bsum[t] = s[t];
}
__global__ void k_scan3(int* __restrict__ off, const int* __restrict__ bsum) {
    int b = blockIdx.x, t = threadIdx.x;
    if (b > 0) off[b * 256 + t + 1] += bsum[b - 1];
    if (b == 0 && t == 0) off[0] = 0;
}
__global__ void k_copy(const int* __restrict__ off, int* __restrict__ cur) {
    int i = blockIdx.x * 256 + threadIdx.x;
    if (i < N_NODES) cur[i] = off[i];
}
__global__ void k_fill(const int* __restrict__ esrc, const int* __restrict__ edst,
                       int* cur, int* __restrict__ srcs) {
    int i = blockIdx.x * 256 + threadIdx.x;
    if (i >= TOT_E) return;
    int s, d;
    if (i < N_EDGES) { s = esrc[i]; d = edst[i]; }
    else             { s = d = i - N_EDGES; }
    int p = atomicAdd(&cur[d], 1);
    srcs[p] = s;
}

// ---------------- GAT aggregation (bf16 features in/out) ----------------
__global__ __launch_bounds__(256) void gat_aggregate(
    const u16* __restrict__ h, const float* __restrict__ aS, const float* __restrict__ aD,
    const int* __restrict__ off, const int* __restrict__ srcs,
    const float* __restrict__ bias, u16* __restrict__ out)
{
    int gid  = blockIdx.x * blockDim.x + threadIdx.x;
    int n    = gid >> 6;
    if (n >= N_NODES) return;
    int lane = threadIdx.x & 63;
    int head = lane >> 3;
    int o0 = off[n], o1 = off[n + 1];
    float aDn = aD[n * HEADS + head];
    float denom = 0.f;
    for (int o = o0; o < o1; ++o) {
        int s = srcs[o];
        float x = aS[s * HEADS + head] + aDn;
        x = x > 0.f ? x : 0.2f * x;
        denom += expf(x);
    }
    float inv = 1.f / (denom + 1e-16f);
    float acc[8] = {};
    for (int o = o0; o < o1; ++o) {
        int s = srcs[o];
        float x = aS[s * HEADS + head] + aDn;
        x = x > 0.f ? x : 0.2f * x;
        float alpha = expf(x) * inv;
        uint4 q = *(const uint4*)(h + (size_t)s * GOUT + lane * 8);
        acc[0] += alpha * bf2f(q.x & 0xffff); acc[1] += alpha * bf2f(q.x >> 16);
        acc[2] += alpha * bf2f(q.y & 0xffff); acc[3] += alpha * bf2f(q.y >> 16);
        acc[4] += alpha * bf2f(q.z & 0xffff); acc[5] += alpha * bf2f(q.z >> 16);
        acc[6] += alpha * bf2f(q.w & 0xffff); acc[7] += alpha * bf2f(q.w >> 16);
    }
    int c0 = lane * 8;
    float r[8];
    #pragma unroll
    for (int j = 0; j < 8; ++j) {
        float v = acc[j] + bias[c0 + j];
        r[j] = v > 0.f ? v : expm1f(v);
    }
    uint4 w;
    w.x = (u32)f2bf(r[0]) | ((u32)f2bf(r[1]) << 16);
    w.y = (u32)f2bf(r[2]) | ((u32)f2bf(r[3]) << 16);
    w.z = (u32)f2bf(r[4]) | ((u32)f2bf(r[5]) << 16);
    w.w = (u32)f2bf(r[6]) | ((u32)f2bf(r[7]) << 16);
    *(uint4*)(out + (size_t)n * GOUT + c0) = w;
}

// ---------------- global mean pool ----------------
__global__ __launch_bounds__(256) void pool_kernel(
    const u16* __restrict__ x, const int* __restrict__ batch, float* __restrict__ cbuf)
{
    int b = blockIdx.x;
    int lo = 0, hi = N_NODES;
    while (lo < hi) { int mid = (lo + hi) >> 1; if (batch[mid] < b) lo = mid + 1; else hi = mid; }
    int start = lo;
    hi = N_NODES;
    while (lo < hi) { int mid = (lo + hi) >> 1; if (batch[mid] < b + 1) lo = mid + 1; else hi = mid; }
    int end = lo;
    int t = threadIdx.x;
    float s0 = 0.f, s1 = 0.f;
    for (int i = start; i < end; ++i) {
        s0 += bf2f(x[(size_t)i * GOUT + t]);
        s1 += bf2f(x[(size_t)i * GOUT + t + 256]);
    }
    float sc = 1.f / fmaxf((float)(end - start), 1.f);
    cbuf[(size_t)b * 1024 + t]       = s0 * sc;
    cbuf[(size_t)b * 1024 + t + 256] = s1 * sc;
}

// ---------------- final dot ----------------
__global__ __launch_bounds__(64) void final_dot(
    const float* __restrict__ f2, const float* __restrict__ w,
    const float* __restrict__ b, float* __restrict__ out)
{
    int row = blockIdx.x, l = threadIdx.x;
    float v = f2[row * 128 + l] * w[l] + f2[row * 128 + 64 + l] * w[64 + l];
    v += __shfl_xor(v, 32); v += __shfl_xor(v, 16); v += __shfl_xor(v, 8);
    v += __shfl_xor(v, 4);  v += __shfl_xor(v, 2);  v += __shfl_xor(v, 1);
    if (l == 0) out[row] = v + b[0];
}

extern "C" void kernel_launch(void* const* d_in, const int* in_sizes, int n_in,
                              void* d_out, int out_size, void* d_ws, size_t ws_size,
                              hipStream_t stream)
{
    const float* x     = (const float*)d_in[0];
    const int*   ei    = (const int*)  d_in[1];
    const int*   batch = (const int*)  d_in[2];
    const float* x_gen = (const float*)d_in[3];
    const float* W1    = (const float*)d_in[4];
    const float* as1   = (const float*)d_in[5];
    const float* ad1   = (const float*)d_in[6];
    const float* b1    = (const float*)d_in[7];
    const float* W2    = (const float*)d_in[8];
    const float* as2   = (const float*)d_in[9];
    const float* ad2   = (const float*)d_in[10];
    const float* b2    = (const float*)d_in[11];
    const float* gW1   = (const float*)d_in[12];
    const float* gb1   = (const float*)d_in[13];
    const float* bng   = (const float*)d_in[14];
    const float* bnb   = (const float*)d_in[15];
    const float* bnm   = (const float*)d_in[16];
    const float* bnv   = (const float*)d_in[17];
    const float* gW2   = (const float*)d_in[18];
    const float* gb2   = (const float*)d_in[19];
    const float* fW1   = (const float*)d_in[20];
    const float* fb1   = (const float*)d_in[21];
    const float* fW2   = (const float*)d_in[22];
    const float* fb2   = (const float*)d_in[23];
    const float* fW3   = (const float*)d_in[24];
    const float* fb3   = (const float*)d_in[25];
    float* out = (float*)d_out;

    char* ws = (char*)d_ws;
    size_t off_b = 0;
    auto alloc = [&](size_t bytes) -> void* {
        void* p = ws + off_b;
        off_b += (bytes + 255) & ~(size_t)255;
        return p;
    };
    u16*   bufA    = (u16*)  alloc((size_t)N_NODES * GOUT * 2);   // bf16 features
    u16*   bufB    = (u16*)  alloc((size_t)N_NODES * GOUT * 2);   // bf16 features
    u16*   xb      = (u16*)  alloc((size_t)N_NODES * K1PAD * 2);  // x bf16, K-padded
    u16*   w1t     = (u16*)  alloc((size_t)GOUT * K1PAD * 2);     // W1^T bf16 padded
    u16*   w2t     = (u16*)  alloc((size_t)GOUT * GOUT * 2);      // W2^T bf16
    float* aSp     = (float*)alloc((size_t)N_NODES * HEADS * 4);
    float* aDp     = (float*)alloc((size_t)N_NODES * HEADS * 4);
    int*   csr_off = (int*)  alloc((size_t)(N_NODES + 1) * 4);
    int*   csr_cur = (int*)  alloc((size_t)N_NODES * 4);
    int*   bsum    = (int*)  alloc(256 * 4);
    int*   csr_src = (int*)  alloc((size_t)TOT_E * 4);
    float* cbuf    = (float*)alloc((size_t)BATCHSZ * 1024 * 4);   // [g | z]
    float* z1b     = (float*)alloc((size_t)BATCHSZ * 128 * 4);
    float* f1b     = (float*)alloc((size_t)BATCHSZ * 256 * 4);
    float* f2b     = (float*)alloc((size_t)BATCHSZ * 128 * 4);

    if (off_b > ws_size) return;   // clean no-op beats a memory fault

    const int* esrc = ei;
    const int* edst = ei + N_EDGES;

    // ---- conversions (bf16 weights/inputs for MFMA) ----
    conv_x_pad<<<(N_NODES * K1PAD) / 256, 256, 0, stream>>>(x, xb);
    conv_w1t<<<(GOUT * K1PAD) / 256, 256, 0, stream>>>(W1, w1t);
    conv_w2t<<<(GOUT * GOUT) / 256, 256, 0, stream>>>(W2, w2t);

    // ---- CSR by destination ----
    k_init_counts<<<N_NODES / 256, 256, 0, stream>>>(csr_cur);
    k_count<<<N_EDGES / 256, 256, 0, stream>>>(edst, csr_cur);
    k_scan1<<<256, 256, 0, stream>>>(csr_cur, csr_off, bsum);
    k_scan2<<<1, 256, 0, stream>>>(bsum);
    k_scan3<<<256, 256, 0, stream>>>(csr_off, bsum);
    k_copy<<<N_NODES / 256, 256, 0, stream>>>(csr_off, csr_cur);
    k_fill<<<TOT_E / 256, 256, 0, stream>>>(esrc, edst, csr_cur, csr_src);

    // ---- GAT layer 1 (MFMA) ----
    dim3 gMF(N_NODES / 128, GOUT / 128);
    gemm_mfma<<<gMF, 256, 0, stream>>>(xb, w1t, bufA, N_NODES, GOUT, K1PAD, GOUT);
    gat_att<<<N_NODES / 4, 256, 0, stream>>>(bufA, as1, ad1, aSp, aDp);
    gat_aggregate<<<N_NODES / 4, 256, 0, stream>>>(bufA, aSp, aDp, csr_off, csr_src, b1, bufB);

    // ---- GAT layer 2 (MFMA) ----
    gemm_mfma<<<gMF, 256, 0, stream>>>(bufB, w2t, bufA, N_NODES, GOUT, GOUT, GOUT);
    gat_att<<<N_NODES / 4, 256, 0, stream>>>(bufA, as2, ad2, aSp, aDp);
    gat_aggregate<<<N_NODES / 4, 256, 0, stream>>>(bufA, aSp, aDp, csr_off, csr_src, b2, bufB);

    // ---- pool ----
    pool_kernel<<<BATCHSZ, 256, 0, stream>>>(bufB, batch, cbuf);

    // ---- genomic encoder (f32, 32x32 tiles for occupancy) ----
    dim3 gG1(BATCHSZ / 32, 128 / 32);
    gemm_small<3><<<gG1, 256, 0, stream>>>(x_gen, gW1, z1b, BATCHSZ, 128, GENES, 128,
                                           gb1, bng, bnb, bnm, bnv);
    dim3 gG2(BATCHSZ / 32, GOUT / 32);
    gemm_small<2><<<gG2, 256, 0, stream>>>(z1b, gW2, cbuf + 512, BATCHSZ, GOUT, 128, 1024,
                                           gb2, nullptr, nullptr, nullptr, nullptr);

    // ---- fusion MLP (f32, 32x32 tiles) ----
    dim3 gF1(BATCHSZ / 32, 256 / 32);
    gemm_small<2><<<gF1, 256, 0, stream>>>(cbuf, fW1, f1b, BATCHSZ, 256, 1024, 256,
                                           fb1, nullptr, nullptr, nullptr, nullptr);
    dim3 gF2(BATCHSZ / 32, 128 / 32);
    gemm_small<2><<<gF2, 256, 0, stream>>>(f1b, fW2, f2b, BATCHSZ, 128, 256, 128,
                                           fb2, nullptr, nullptr, nullptr, nullptr);
    final_dot<<<BATCHSZ, 64, 0, stream>>>(f2b, fW3, fb3, out);
}

// Round 8
// 695.511 us; speedup vs baseline: 2.6370x; 1.0530x over previous
//
#include <hip/hip_runtime.h>
#include <hip/hip_bf16.h>
#include <math.h>

#define N_NODES 65536
#define N_EDGES 262144
#define BATCHSZ 2048
#define F_IN    78
#define K1PAD   96
#define GENES   735
#define GOUT    512
#define HEADS   8
#define HID     64
#define TOT_E   (N_EDGES + N_NODES)   // 327680

typedef unsigned short u16;
typedef unsigned int   u32;
typedef __attribute__((ext_vector_type(4))) float f32x4;
typedef __attribute__((ext_vector_type(8))) short bf16x8;

__device__ __forceinline__ float bf2f(u32 h) {
    u32 u = h << 16;
    return __uint_as_float(u);
}
__device__ __forceinline__ u16 f2bf(float f) {
    u32 u = __float_as_uint(f);
    u32 r = (u + 0x7FFFu + ((u >> 16) & 1u)) >> 16;   // round-to-nearest-even
    return (u16)r;
}

// ================= MFMA bf16 GEMM (node-feature GEMMs) =================
__global__ __launch_bounds__(256) void gemm_mfma(
    const u16* __restrict__ A, const u16* __restrict__ BT, u16* __restrict__ C,
    int M, int N, int K, int ldc)
{
    __shared__ u16 Al[128 * 40];
    __shared__ u16 Bl[128 * 40];
    int t    = threadIdx.x;
    int wid  = t >> 6, lane = t & 63;
    int wm   = wid >> 1, wn = wid & 1;
    int bm   = blockIdx.x * 128, bn = blockIdx.y * 128;

    f32x4 acc[4][4] = {};

    for (int k0 = 0; k0 < K; k0 += 32) {
        #pragma unroll
        for (int i = 0; i < 2; ++i) {
            int flat = t + i * 256;          // 0..511
            int row  = flat >> 2, slot = flat & 3;
            uint4 va = *(const uint4*)(A  + (size_t)(bm + row) * K + k0 + slot * 8);
            *(uint4*)(Al + row * 40 + slot * 8) = va;
            uint4 vb = *(const uint4*)(BT + (size_t)(bn + row) * K + k0 + slot * 8);
            *(uint4*)(Bl + row * 40 + slot * 8) = vb;
        }
        __syncthreads();
        bf16x8 af[4], bfr[4];
        int r0 = wm * 64 + (lane & 15);
        int c0 = wn * 64 + (lane & 15);
        int kk = (lane >> 4) * 8;
        #pragma unroll
        for (int m = 0; m < 4; ++m)
            af[m] = *(const bf16x8*)(Al + (r0 + m * 16) * 40 + kk);
        #pragma unroll
        for (int n = 0; n < 4; ++n)
            bfr[n] = *(const bf16x8*)(Bl + (c0 + n * 16) * 40 + kk);
        #pragma unroll
        for (int m = 0; m < 4; ++m)
            #pragma unroll
            for (int n = 0; n < 4; ++n)
                acc[m][n] = __builtin_amdgcn_mfma_f32_16x16x32_bf16(af[m], bfr[n], acc[m][n], 0, 0, 0);
        __syncthreads();
    }
    int rbase = bm + wm * 64 + (lane >> 4) * 4;
    int cbase = bn + wn * 64 + (lane & 15);
    #pragma unroll
    for (int m = 0; m < 4; ++m)
        #pragma unroll
        for (int n = 0; n < 4; ++n) {
            int col = cbase + n * 16;
            #pragma unroll
            for (int j = 0; j < 4; ++j) {
                int row = rbase + m * 16 + j;
                C[(size_t)row * ldc + col] = f2bf(acc[m][n][j]);
            }
        }
}

// ---- weight/input conversion: f32 -> bf16 (optionally transposed / K-padded) ----
__global__ void conv_x_pad(const float* __restrict__ x, u16* __restrict__ xb) {
    int i = blockIdx.x * 256 + threadIdx.x;          // over N_NODES*K1PAD
    int row = i / K1PAD, col = i - row * K1PAD;
    xb[i] = (col < F_IN) ? f2bf(x[(size_t)row * F_IN + col]) : (u16)0;
}
__global__ void conv_w1t(const float* __restrict__ W, u16* __restrict__ WT) {
    int i = blockIdx.x * 256 + threadIdx.x;          // over GOUT*K1PAD
    int n = i / K1PAD, k = i - n * K1PAD;
    WT[i] = (k < F_IN) ? f2bf(W[(size_t)k * GOUT + n]) : (u16)0;
}
__global__ void conv_w2t(const float* __restrict__ W, u16* __restrict__ WT) {
    int i = blockIdx.x * 256 + threadIdx.x;          // over GOUT*GOUT
    int n = i >> 9, k = i & 511;
    WT[i] = f2bf(W[(size_t)k * GOUT + n]);
}

// ---------------- small-GEMM: 32x32 tile, f32, high grid parallelism ----------------
template<int EPI>
__global__ __launch_bounds__(256) void gemm_small(
    const float* __restrict__ A, const float* __restrict__ B, float* __restrict__ C,
    int M, int N, int K, int ldc,
    const float* __restrict__ bias,
    const float* __restrict__ bng, const float* __restrict__ bnb,
    const float* __restrict__ bnm, const float* __restrict__ bnv)
{
    __shared__ float As[32][33];
    __shared__ float Bs[32][33];
    int t  = threadIdx.x;
    int bm = blockIdx.x * 32, bn = blockIdx.y * 32;
    int ty = t >> 4, tx = t & 15;          // 16x16 threads, 2x2 each
    float acc[2][2] = {};
    for (int k0 = 0; k0 < K; k0 += 32) {
        #pragma unroll
        for (int i = 0; i < 4; ++i) {
            int idx = t + i * 256;
            int r = idx >> 5, kk = idx & 31;
            int gr = bm + r, gk = k0 + kk;
            As[r][kk] = (gr < M && gk < K) ? A[(size_t)gr * K + gk] : 0.f;
            int kr = idx >> 5, c = idx & 31;
            int gk2 = k0 + kr, gc = bn + c;
            Bs[kr][c] = (gk2 < K && gc < N) ? B[(size_t)gk2 * N + gc] : 0.f;
        }
        __syncthreads();
        #pragma unroll
        for (int k = 0; k < 32; ++k) {
            float a0 = As[ty*2+0][k], a1 = As[ty*2+1][k];
            float b0 = Bs[k][tx*2+0], b1 = Bs[k][tx*2+1];
            acc[0][0] += a0*b0; acc[0][1] += a0*b1;
            acc[1][0] += a1*b0; acc[1][1] += a1*b1;
        }
        __syncthreads();
    }
    #pragma unroll
    for (int i = 0; i < 2; ++i) {
        int gr = bm + ty*2 + i;
        if (gr >= M) continue;
        #pragma unroll
        for (int j = 0; j < 2; ++j) {
            int gc = bn + tx*2 + j;
            if (gc >= N) continue;
            float v = acc[i][j];
            if (EPI == 2) { v += bias[gc]; v = fmaxf(v, 0.f); }
            if (EPI == 3) {
                float s = bng[gc] * rsqrtf(bnv[gc] + 1e-5f);
                v = (v + bias[gc] - bnm[gc]) * s + bnb[gc];
                v = fmaxf(v, 0.f);
            }
            C[(size_t)gr * ldc + gc] = v;
        }
    }
}

// ---------------- attention coefficients from bf16 features ----------------
__global__ __launch_bounds__(256) void gat_att(
    const u16* __restrict__ h,
    const float* __restrict__ att_src, const float* __restrict__ att_dst,
    float* __restrict__ aS, float* __restrict__ aD)
{
    int gid  = blockIdx.x * blockDim.x + threadIdx.x;
    int n    = gid >> 6;
    int lane = threadIdx.x & 63;
    if (n >= N_NODES) return;
    int head = lane >> 3;
    int ci   = (lane & 7) * 8;
    uint4 q = *(const uint4*)(h + (size_t)n * GOUT + lane * 8);
    float h0 = bf2f(q.x & 0xffff), h1 = bf2f(q.x >> 16);
    float h2 = bf2f(q.y & 0xffff), h3 = bf2f(q.y >> 16);
    float h4 = bf2f(q.z & 0xffff), h5 = bf2f(q.z >> 16);
    float h6 = bf2f(q.w & 0xffff), h7 = bf2f(q.w >> 16);
    const float* as = att_src + head * HID + ci;
    const float* ad = att_dst + head * HID + ci;
    float ss = h0*as[0] + h1*as[1] + h2*as[2] + h3*as[3]
             + h4*as[4] + h5*as[5] + h6*as[6] + h7*as[7];
    float dd = h0*ad[0] + h1*ad[1] + h2*ad[2] + h3*ad[3]
             + h4*ad[4] + h5*ad[5] + h6*ad[6] + h7*ad[7];
    ss += __shfl_xor(ss, 1); ss += __shfl_xor(ss, 2); ss += __shfl_xor(ss, 4);
    dd += __shfl_xor(dd, 1); dd += __shfl_xor(dd, 2); dd += __shfl_xor(dd, 4);
    if ((lane & 7) == 0) {
        aS[n * HEADS + head] = ss;
        aD[n * HEADS + head] = dd;
    }
}

// ---------------- CSR build ----------------
__global__ void k_init_counts(int* cnt) {
    int i = blockIdx.x * 256 + threadIdx.x;
    if (i < N_NODES) cnt[i] = 1;             // self-loop
}
__global__ void k_count(const int* __restrict__ dst, int* cnt) {
    int e = blockIdx.x * 256 + threadIdx.x;
    if (e < N_EDGES) atomicAdd(&cnt[dst[e]], 1);
}
__global__ void k_scan1(const int* __restrict__ cnt, int* __restrict__ off, int* __restrict__ bsum) {
    __shared__ int s[256];
    int b = blockIdx.x, t = threadIdx.x;
    s[t] = cnt[b * 256 + t]; __syncthreads();
    for (int d = 1; d < 256; d <<= 1) {
        int x = (t >= d) ? s[t - d] : 0;
        __syncthreads();
        s[t] += x;
        __syncthreads();
    }
    off[b * 256 + t + 1] = s[t];
    if (t == 255) bsum[b] = s[255];
}
__global__ void k_scan2(int* bsum) {
    __shared__ int s[256];
    int t = threadIdx.x;
    s[t] = bsum[t]; __syncthreads();
    for (int d = 1; d < 256; d <<= 1) {
        int x = (t >= d) ? s[t - d] : 0;
        __syncthreads();
        s[t] += x;
        __syncthreads();
    }
    bsum[t] = s[t];
}
__global__ void k_scan3(int* __restrict__ off, const int* __restrict__ bsum) {
    int b = blockIdx.x, t = threadIdx.x;
    if (b > 0) off[b * 256 + t + 1] += bsum[b - 1];
    if (b == 0 && t == 0) off[0] = 0;
}
__global__ void k_copy(const int* __restrict__ off, int* __restrict__ cur) {
    int i = blockIdx.x * 256 + threadIdx.x;
    if (i < N_NODES) cur[i] = off[i];
}
__global__ void k_fill(const int* __restrict__ esrc, const int* __restrict__ edst,
                       int* cur, int* __restrict__ srcs, int* __restrict__ dsts) {
    int i = blockIdx.x * 256 + threadIdx.x;
    if (i >= TOT_E) return;
    int s, d;
    if (i < N_EDGES) { s = esrc[i]; d = edst[i]; }
    else             { s = d = i - N_EDGES; }
    int p = atomicAdd(&cur[d], 1);
    srcs[p] = s;
    dsts[p] = d;
}

// ---------------- per-(edge,head) unnormalized attention weight ----------------
// ealpha[o][h] = exp(leaky_relu(aS[src_o][h] + aD[dst_o][h]))
__global__ __launch_bounds__(256) void edge_alpha(
    const int* __restrict__ srcs, const int* __restrict__ dsts,
    const float* __restrict__ aS, const float* __restrict__ aD,
    float* __restrict__ ealpha)
{
    int i = blockIdx.x * 256 + threadIdx.x;      // over TOT_E*HEADS
    int o = i >> 3, h = i & 7;
    int s = srcs[o], d = dsts[o];
    float x = aS[s * HEADS + h] + aD[d * HEADS + h];
    x = x > 0.f ? x : 0.2f * x;
    ealpha[i] = expf(x);
}

// ---------------- GAT aggregation: single pass, precomputed weights ----------------
// out[n,:] = ELU( (1/(sum_e e + eps)) * sum_e e * h[src_e,:] + bias )
__global__ __launch_bounds__(256) void gat_aggregate(
    const u16* __restrict__ h, const float* __restrict__ ealpha,
    const int* __restrict__ off, const int* __restrict__ srcs,
    const float* __restrict__ bias, u16* __restrict__ out)
{
    int gid  = blockIdx.x * blockDim.x + threadIdx.x;
    int n    = gid >> 6;
    if (n >= N_NODES) return;
    int lane = threadIdx.x & 63;
    int head = lane >> 3;
    int o0 = off[n], o1 = off[n + 1];
    float denom = 0.f;
    float acc[8] = {};
    for (int o = o0; o < o1; ++o) {
        int s = srcs[o];
        float e = ealpha[o * HEADS + head];
        denom += e;
        uint4 q = *(const uint4*)(h + (size_t)s * GOUT + lane * 8);
        acc[0] += e * bf2f(q.x & 0xffff); acc[1] += e * bf2f(q.x >> 16);
        acc[2] += e * bf2f(q.y & 0xffff); acc[3] += e * bf2f(q.y >> 16);
        acc[4] += e * bf2f(q.z & 0xffff); acc[5] += e * bf2f(q.z >> 16);
        acc[6] += e * bf2f(q.w & 0xffff); acc[7] += e * bf2f(q.w >> 16);
    }
    float inv = 1.f / (denom + 1e-16f);
    int c0 = lane * 8;
    float r[8];
    #pragma unroll
    for (int j = 0; j < 8; ++j) {
        float v = acc[j] * inv + bias[c0 + j];
        r[j] = v > 0.f ? v : expm1f(v);
    }
    uint4 w;
    w.x = (u32)f2bf(r[0]) | ((u32)f2bf(r[1]) << 16);
    w.y = (u32)f2bf(r[2]) | ((u32)f2bf(r[3]) << 16);
    w.z = (u32)f2bf(r[4]) | ((u32)f2bf(r[5]) << 16);
    w.w = (u32)f2bf(r[6]) | ((u32)f2bf(r[7]) << 16);
    *(uint4*)(out + (size_t)n * GOUT + c0) = w;
}

// ---------------- global mean pool ----------------
__global__ __launch_bounds__(256) void pool_kernel(
    const u16* __restrict__ x, const int* __restrict__ batch, float* __restrict__ cbuf)
{
    int b = blockIdx.x;
    int lo = 0, hi = N_NODES;
    while (lo < hi) { int mid = (lo + hi) >> 1; if (batch[mid] < b) lo = mid + 1; else hi = mid; }
    int start = lo;
    hi = N_NODES;
    while (lo < hi) { int mid = (lo + hi) >> 1; if (batch[mid] < b + 1) lo = mid + 1; else hi = mid; }
    int end = lo;
    int t = threadIdx.x;
    float s0 = 0.f, s1 = 0.f;
    for (int i = start; i < end; ++i) {
        s0 += bf2f(x[(size_t)i * GOUT + t]);
        s1 += bf2f(x[(size_t)i * GOUT + t + 256]);
    }
    float sc = 1.f / fmaxf((float)(end - start), 1.f);
    cbuf[(size_t)b * 1024 + t]       = s0 * sc;
    cbuf[(size_t)b * 1024 + t + 256] = s1 * sc;
}

// ---------------- final dot ----------------
__global__ __launch_bounds__(64) void final_dot(
    const float* __restrict__ f2, const float* __restrict__ w,
    const float* __restrict__ b, float* __restrict__ out)
{
    int row = blockIdx.x, l = threadIdx.x;
    float v = f2[row * 128 + l] * w[l] + f2[row * 128 + 64 + l] * w[64 + l];
    v += __shfl_xor(v, 32); v += __shfl_xor(v, 16); v += __shfl_xor(v, 8);
    v += __shfl_xor(v, 4);  v += __shfl_xor(v, 2);  v += __shfl_xor(v, 1);
    if (l == 0) out[row] = v + b[0];
}

extern "C" void kernel_launch(void* const* d_in, const int* in_sizes, int n_in,
                              void* d_out, int out_size, void* d_ws, size_t ws_size,
                              hipStream_t stream)
{
    const float* x     = (const float*)d_in[0];
    const int*   ei    = (const int*)  d_in[1];
    const int*   batch = (const int*)  d_in[2];
    const float* x_gen = (const float*)d_in[3];
    const float* W1    = (const float*)d_in[4];
    const float* as1   = (const float*)d_in[5];
    const float* ad1   = (const float*)d_in[6];
    const float* b1    = (const float*)d_in[7];
    const float* W2    = (const float*)d_in[8];
    const float* as2   = (const float*)d_in[9];
    const float* ad2   = (const float*)d_in[10];
    const float* b2    = (const float*)d_in[11];
    const float* gW1   = (const float*)d_in[12];
    const float* gb1   = (const float*)d_in[13];
    const float* bng   = (const float*)d_in[14];
    const float* bnb   = (const float*)d_in[15];
    const float* bnm   = (const float*)d_in[16];
    const float* bnv   = (const float*)d_in[17];
    const float* gW2   = (const float*)d_in[18];
    const float* gb2   = (const float*)d_in[19];
    const float* fW1   = (const float*)d_in[20];
    const float* fb1   = (const float*)d_in[21];
    const float* fW2   = (const float*)d_in[22];
    const float* fb2   = (const float*)d_in[23];
    const float* fW3   = (const float*)d_in[24];
    const float* fb3   = (const float*)d_in[25];
    float* out = (float*)d_out;

    char* ws = (char*)d_ws;
    size_t off_b = 0;
    auto alloc = [&](size_t bytes) -> void* {
        void* p = ws + off_b;
        off_b += (bytes + 255) & ~(size_t)255;
        return p;
    };
    u16*   bufA    = (u16*)  alloc((size_t)N_NODES * GOUT * 2);   // bf16 features
    u16*   bufB    = (u16*)  alloc((size_t)N_NODES * GOUT * 2);   // bf16 features
    u16*   xb      = (u16*)  alloc((size_t)N_NODES * K1PAD * 2);  // x bf16, K-padded
    u16*   w1t     = (u16*)  alloc((size_t)GOUT * K1PAD * 2);     // W1^T bf16 padded
    u16*   w2t     = (u16*)  alloc((size_t)GOUT * GOUT * 2);      // W2^T bf16
    float* aSp     = (float*)alloc((size_t)N_NODES * HEADS * 4);
    float* aDp     = (float*)alloc((size_t)N_NODES * HEADS * 4);
    int*   csr_off = (int*)  alloc((size_t)(N_NODES + 1) * 4);
    int*   csr_cur = (int*)  alloc((size_t)N_NODES * 4);
    int*   bsum    = (int*)  alloc(256 * 4);
    int*   csr_src = (int*)  alloc((size_t)TOT_E * 4);
    int*   csr_dst = (int*)  alloc((size_t)TOT_E * 4);
    float* ealpha  = (float*)alloc((size_t)TOT_E * HEADS * 4);
    float* cbuf    = (float*)alloc((size_t)BATCHSZ * 1024 * 4);   // [g | z]
    float* z1b     = (float*)alloc((size_t)BATCHSZ * 128 * 4);
    float* f1b     = (float*)alloc((size_t)BATCHSZ * 256 * 4);
    float* f2b     = (float*)alloc((size_t)BATCHSZ * 128 * 4);

    if (off_b > ws_size) return;   // clean no-op beats a memory fault

    const int* esrc = ei;
    const int* edst = ei + N_EDGES;

    // ---- conversions (bf16 weights/inputs for MFMA) ----
    conv_x_pad<<<(N_NODES * K1PAD) / 256, 256, 0, stream>>>(x, xb);
    conv_w1t<<<(GOUT * K1PAD) / 256, 256, 0, stream>>>(W1, w1t);
    conv_w2t<<<(GOUT * GOUT) / 256, 256, 0, stream>>>(W2, w2t);

    // ---- CSR by destination ----
    k_init_counts<<<N_NODES / 256, 256, 0, stream>>>(csr_cur);
    k_count<<<N_EDGES / 256, 256, 0, stream>>>(edst, csr_cur);
    k_scan1<<<256, 256, 0, stream>>>(csr_cur, csr_off, bsum);
    k_scan2<<<1, 256, 0, stream>>>(bsum);
    k_scan3<<<256, 256, 0, stream>>>(csr_off, bsum);
    k_copy<<<N_NODES / 256, 256, 0, stream>>>(csr_off, csr_cur);
    k_fill<<<TOT_E / 256, 256, 0, stream>>>(esrc, edst, csr_cur, csr_src, csr_dst);

    // ---- GAT layer 1 (MFMA) ----
    dim3 gMF(N_NODES / 128, GOUT / 128);
    gemm_mfma<<<gMF, 256, 0, stream>>>(xb, w1t, bufA, N_NODES, GOUT, K1PAD, GOUT);
    gat_att<<<N_NODES / 4, 256, 0, stream>>>(bufA, as1, ad1, aSp, aDp);
    edge_alpha<<<(TOT_E * HEADS) / 256, 256, 0, stream>>>(csr_src, csr_dst, aSp, aDp, ealpha);
    gat_aggregate<<<N_NODES / 4, 256, 0, stream>>>(bufA, ealpha, csr_off, csr_src, b1, bufB);

    // ---- GAT layer 2 (MFMA) ----
    gemm_mfma<<<gMF, 256, 0, stream>>>(bufB, w2t, bufA, N_NODES, GOUT, GOUT, GOUT);
    gat_att<<<N_NODES / 4, 256, 0, stream>>>(bufA, as2, ad2, aSp, aDp);
    edge_alpha<<<(TOT_E * HEADS) / 256, 256, 0, stream>>>(csr_src, csr_dst, aSp, aDp, ealpha);
    gat_aggregate<<<N_NODES / 4, 256, 0, stream>>>(bufA, ealpha, csr_off, csr_src, b2, bufB);

    // ---- pool ----
    pool_kernel<<<BATCHSZ, 256, 0, stream>>>(bufB, batch, cbuf);

    // ---- genomic encoder (f32, 32x32 tiles for occupancy) ----
    dim3 gG1(BATCHSZ / 32, 128 / 32);
    gemm_small<3><<<gG1, 256, 0, stream>>>(x_gen, gW1, z1b, BATCHSZ, 128, GENES, 128,
                                           gb1, bng, bnb, bnm, bnv);
    dim3 gG2(BATCHSZ / 32, GOUT / 32);
    gemm_small<2><<<gG2, 256, 0, stream>>>(z1b, gW2, cbuf + 512, BATCHSZ, GOUT, 128, 1024,
                                           gb2, nullptr, nullptr, nullptr, nullptr);

    // ---- fusion MLP (f32, 32x32 tiles) ----
    dim3 gF1(BATCHSZ / 32, 256 / 32);
    gemm_small<2><<<gF1, 256, 0, stream>>>(cbuf, fW1, f1b, BATCHSZ, 256, 1024, 256,
                                           fb1, nullptr, nullptr, nullptr, nullptr);
    dim3 gF2(BATCHSZ / 32, 128 / 32);
    gemm_small<2><<<gF2, 256, 0, stream>>>(f1b, fW2, f2b, BATCHSZ, 128, 256, 128,
                                           fb2, nullptr, nullptr, nullptr, nullptr);
    final_dot<<<BATCHSZ, 64, 0, stream>>>(f2b, fW3, fb3, out);
}